// Round 6
// baseline (80.124 us; speedup 1.0000x reference)
//
#include <hip/hip_runtime.h>

#define H 1536
#define BD 128
#define ROWS 16
#define NTHREADS 512
#define NBLOCKS 1024   // 16384 rows / 16

using f16x8 = _Float16 __attribute__((ext_vector_type(8)));
using f32x4 = float __attribute__((ext_vector_type(4)));
using i64x2 = long __attribute__((ext_vector_type(2)));

// Weights |w| <= 6e-4 are BELOW e4m3's denormal floor (2^-9) -> pre-scale by
// 2^14. t stored as t*2^7 in fp8; x stored as x*2^17 in fp8; descale 2^-17.
#define WD_SCALE 16384.0f           // 2^14
#define T8_SCALE (1.0f/128.0f)      // acc1(=t*2^14) * 2^-7 = t*2^7
#define X8_STORE (1.0f/16.0f)       // acc2(=x*2^21) * 2^-4 = x*2^17 (max ~45 < 448)
#define XF_SCALE (1.0f/131072.0f)   // 2^-17

// ---------------------------------------------------------------------------
// Kernel 0: pack weights fp32 -> fp8(e4m3, x2^14), pair-interleaved fragment
// order (unchanged from R5, verified).
// ---------------------------------------------------------------------------
__global__ __launch_bounds__(256) void pack_weights(const float* __restrict__ wd,
                                                    const float* __restrict__ wu,
                                                    char* __restrict__ wdp8,
                                                    char* __restrict__ wup8) {
    int f = blockIdx.x * 256 + threadIdx.x;   // 0..49151
    const float* src;
    char* dst;
    if (f < 24576) {
        int w = f / 3072, rem = f - w * 3072;
        int ph = rem >> 6, l = rem & 63;      // ph = frag index 0..47
        int row = 16 * w + (l & 15);
        int col = 32 * ph + 8 * (l >> 4);
        src = wd + (size_t)row * H + col;     // Wd is [128][1536]
        int p = ph >> 1, half = ph & 1;
        dst = wdp8 + (((size_t)(w * 24 + p) * 64 + l) * 16 + half * 8);
    } else {
        int g = f - 24576;
        int w = g / 3072, rem = g - w * 3072;
        int t2 = rem >> 6, l = rem & 63;      // t2 = nf*4 + kf
        int nf = t2 >> 2, kf = t2 & 3;
        int row = 192 * w + 16 * nf + (l & 15);
        int col = 32 * kf + 8 * (l >> 4);
        src = wu + (size_t)row * BD + col;    // Wu is [1536][128]
        int q = nf * 2 + (kf >> 1), half = kf & 1;
        dst = wup8 + (((size_t)(w * 24 + q) * 64 + l) * 16 + half * 8);
    }
    float4 v0 = reinterpret_cast<const float4*>(src)[0];
    float4 v1 = reinterpret_cast<const float4*>(src)[1];
    int i0 = __builtin_amdgcn_cvt_pk_fp8_f32(v0.x * WD_SCALE, v0.y * WD_SCALE, 0, false);
    i0     = __builtin_amdgcn_cvt_pk_fp8_f32(v0.z * WD_SCALE, v0.w * WD_SCALE, i0, true);
    int i1 = __builtin_amdgcn_cvt_pk_fp8_f32(v1.x * WD_SCALE, v1.y * WD_SCALE, 0, false);
    i1     = __builtin_amdgcn_cvt_pk_fp8_f32(v1.z * WD_SCALE, v1.w * WD_SCALE, i1, true);
    int2 st = {i0, i1};
    *reinterpret_cast<int2*>(dst) = st;
}

// ---------------------------------------------------------------------------
// Fused adapter. hs lives in VGPRs end-to-end (stage mapping == final
// mapping); only x (tiny, fp8-safe) crosses waves via LDS. x8 overlays the
// dead hsa8; reductions overlay the dead tb8. LDS = 26624 B.
// ---------------------------------------------------------------------------
__global__ __launch_bounds__(NTHREADS, 4) void fused_adapter(
    const float* __restrict__ hs,
    const char* __restrict__ wdp8,
    const char* __restrict__ wup8,
    const float* __restrict__ gamma,
    const float* __restrict__ beta,
    float* __restrict__ out)
{
    __shared__ alignas(16) char smem[26624];
    char* hsa8    = smem;                                     // [48 frag][64][8B]
    char* x8      = smem;                                     // overlay: [16][1536] fp8
    char* tb8     = smem + 24576;                             // [4 frag][64][8B]
    float* redS   = reinterpret_cast<float*>(smem + 24576);   // overlay tb8: [48]
    float* redQ   = redS + 48;
    float* statsM = redQ + 48;                                // [16]
    float* statsR = statsM + 16;                              // [16]

    const int tid  = threadIdx.x;
    const int lane = tid & 63;
    const int w    = tid >> 6;        // wave 0..7
    const int l15  = lane & 15;
    const int lk   = lane >> 4;       // 0..3
    const long row0 = (long)blockIdx.x * ROWS;
    const float* hsblk = hs + row0 * H;

    const i64x2* wp2 = reinterpret_cast<const i64x2*>(wdp8) + (size_t)w * 24 * 64 + lane;
    const i64x2* up2 = reinterpret_cast<const i64x2*>(wup8) + (size_t)w * 24 * 64 + lane;

    // ---- prefetch first 4 Wd pairs (hides L2 latency under staging)
    i64x2 bq[4];
    bq[0] = wp2[0 * 64]; bq[1] = wp2[1 * 64]; bq[2] = wp2[2 * 64]; bq[3] = wp2[3 * 64];

    // ---- stage: load hs into REGISTERS (kept through entire kernel), write
    // fp8 copy to hsa8 in GEMM1 A-fragment order.
    float4 va[6], vb[6];
#pragma unroll
    for (int i = 0; i < 6; ++i) {
        int c  = tid + NTHREADS * i;
        int r  = c / 192;
        int c8 = c - r * 192;
        const float4* p = reinterpret_cast<const float4*>(hsblk + (long)r * H + c8 * 8);
        va[i] = p[0];
        vb[i] = p[1];
    }
#pragma unroll
    for (int i = 0; i < 6; ++i) {
        int c  = tid + NTHREADS * i;
        int r  = c / 192;
        int c8 = c - r * 192;
        int j0 = __builtin_amdgcn_cvt_pk_fp8_f32(va[i].x, va[i].y, 0, false);
        j0     = __builtin_amdgcn_cvt_pk_fp8_f32(va[i].z, va[i].w, j0, true);
        int j1 = __builtin_amdgcn_cvt_pk_fp8_f32(vb[i].x, vb[i].y, 0, false);
        j1     = __builtin_amdgcn_cvt_pk_fp8_f32(vb[i].z, vb[i].w, j1, true);
        int kk = c8 >> 2, m = c8 & 3;
        int al = (16 * m + r) ^ ((kk & 15) << 1);   // bank swizzle (R5-verified)
        int2 stv = {j0, j1};
        *reinterpret_cast<int2*>(&hsa8[(kk * 64 + al) * 8]) = stv;
    }
    __syncthreads();                                // B1: hsa8 ready

    // ---- GEMM1 (fp8): t = hs @ Wd^T; wave w owns t-cols 16w..16w+15.
    f32x4 accv[4] = {{0,0,0,0},{0,0,0,0},{0,0,0,0},{0,0,0,0}};
#pragma unroll
    for (int p = 0; p < 24; ++p) {
        int kk0 = 2 * p, kk1 = 2 * p + 1;
        long alo = *reinterpret_cast<const long*>(&hsa8[(kk0 * 64 + (lane ^ ((kk0 & 15) << 1))) * 8]);
        long ahi = *reinterpret_cast<const long*>(&hsa8[(kk1 * 64 + (lane ^ ((kk1 & 15) << 1))) * 8]);
        i64x2 b = bq[p & 3];
        if (p + 4 < 24) bq[p & 3] = wp2[(p + 4) * 64];
        f32x4 a = accv[p & 3];
        a = __builtin_amdgcn_mfma_f32_16x16x32_fp8_fp8(alo, b[0], a, 0, 0, 0);
        a = __builtin_amdgcn_mfma_f32_16x16x32_fp8_fp8(ahi, b[1], a, 0, 0, 0);
        accv[p & 3] = a;
    }

    // ---- prefetch first 4 Wu pairs (covers tb8 round-trip + barrier)
    i64x2 uq[4];
    uq[0] = up2[0 * 64]; uq[1] = up2[1 * 64]; uq[2] = up2[2 * 64]; uq[3] = up2[3 * 64];

    // ---- t -> fp8 tb8 (t*2^7), GEMM2 A-fragment order (R5-verified mapping)
    {
        f32x4 a1 = (accv[0] + accv[1]) + (accv[2] + accv[3]);
        int p0 = __builtin_amdgcn_cvt_pk_fp8_f32(a1[0] * T8_SCALE, a1[1] * T8_SCALE, 0, false);
        int p1 = __builtin_amdgcn_cvt_pk_fp8_f32(a1[2] * T8_SCALE, a1[3] * T8_SCALE, 0, false);
        int kk2 = w >> 1;
        int lane_hi = 2 * (w & 1) + (l15 >> 3);
        int e8 = l15 & 7;
        int base = (kk2 * 64 + 16 * lane_hi + 4 * lk) * 8 + e8;
        tb8[base + 0 * 8] = (char)(p0 & 0xFF);
        tb8[base + 1 * 8] = (char)((p0 >> 8) & 0xFF);
        tb8[base + 2 * 8] = (char)(p1 & 0xFF);
        tb8[base + 3 * 8] = (char)((p1 >> 8) & 0xFF);
    }
    __syncthreads();                                // B2: tb8 ready (GEMM1 done)

    long a2f8[4];
#pragma unroll
    for (int kf = 0; kf < 4; ++kf)
        a2f8[kf] = *reinterpret_cast<const long*>(&tb8[(kf * 64 + lane) * 8]);

    // ---- GEMM2 (fp8): x = t @ Wu^T; write x as fp8 bytes into x8 (overlay
    // of hsa8 — safe: all GEMM1 reads completed before B2).
#pragma unroll
    for (int nf = 0; nf < 12; ++nf) {
        i64x2 u0 = uq[(2 * nf) & 3];
        i64x2 u1 = uq[(2 * nf + 1) & 3];
        if (2 * nf + 4 < 24) uq[(2 * nf) & 3]     = up2[(2 * nf + 4) * 64];
        if (2 * nf + 5 < 24) uq[(2 * nf + 1) & 3] = up2[(2 * nf + 5) * 64];
        f32x4 acc = {0.f, 0.f, 0.f, 0.f};
        acc = __builtin_amdgcn_mfma_f32_16x16x32_fp8_fp8(a2f8[0], u0[0], acc, 0, 0, 0);
        acc = __builtin_amdgcn_mfma_f32_16x16x32_fp8_fp8(a2f8[1], u0[1], acc, 0, 0, 0);
        acc = __builtin_amdgcn_mfma_f32_16x16x32_fp8_fp8(a2f8[2], u1[0], acc, 0, 0, 0);
        acc = __builtin_amdgcn_mfma_f32_16x16x32_fp8_fp8(a2f8[3], u1[1], acc, 0, 0, 0);
        int cn = 192 * w + 16 * nf + l15;
        int p0 = __builtin_amdgcn_cvt_pk_fp8_f32(acc[0] * X8_STORE, acc[1] * X8_STORE, 0, false);
        int p1 = __builtin_amdgcn_cvt_pk_fp8_f32(acc[2] * X8_STORE, acc[3] * X8_STORE, 0, false);
        x8[(4 * lk + 0) * H + cn] = (char)(p0 & 0xFF);
        x8[(4 * lk + 1) * H + cn] = (char)((p0 >> 8) & 0xFF);
        x8[(4 * lk + 2) * H + cn] = (char)(p1 & 0xFF);
        x8[(4 * lk + 3) * H + cn] = (char)(p1 >> 8 & 0xFF);
    }
    __syncthreads();                                // B3: x8 ready (tb8 dead)

    // ---- y = hs(regs, f32) + x(fp8): stats. Each (wave, iter) 64-chunk lies
    // in exactly one row (192 = 3*64) -> full-wave shfl reduce, 3 partials/row.
    float sums[6], sumq[6];
#pragma unroll
    for (int i = 0; i < 6; ++i) {
        int c  = tid + NTHREADS * i;
        int r  = c / 192;
        int c8 = c - r * 192;
        int2 xw = *reinterpret_cast<const int2*>(&x8[r * H + c8 * 8]);
        va[i].x += __builtin_amdgcn_cvt_f32_fp8(xw.x, 0) * XF_SCALE;
        va[i].y += __builtin_amdgcn_cvt_f32_fp8(xw.x, 1) * XF_SCALE;
        va[i].z += __builtin_amdgcn_cvt_f32_fp8(xw.x, 2) * XF_SCALE;
        va[i].w += __builtin_amdgcn_cvt_f32_fp8(xw.x, 3) * XF_SCALE;
        vb[i].x += __builtin_amdgcn_cvt_f32_fp8(xw.y, 0) * XF_SCALE;
        vb[i].y += __builtin_amdgcn_cvt_f32_fp8(xw.y, 1) * XF_SCALE;
        vb[i].z += __builtin_amdgcn_cvt_f32_fp8(xw.y, 2) * XF_SCALE;
        vb[i].w += __builtin_amdgcn_cvt_f32_fp8(xw.y, 3) * XF_SCALE;
        float s = (va[i].x + va[i].y) + (va[i].z + va[i].w)
                + (vb[i].x + vb[i].y) + (vb[i].z + vb[i].w);
        float q = (va[i].x * va[i].x + va[i].y * va[i].y)
                + (va[i].z * va[i].z + va[i].w * va[i].w)
                + (vb[i].x * vb[i].x + vb[i].y * vb[i].y)
                + (vb[i].z * vb[i].z + vb[i].w * vb[i].w);
        sums[i] = s; sumq[i] = q;
    }
#pragma unroll
    for (int i = 0; i < 6; ++i) {
#pragma unroll
        for (int off = 1; off < 64; off <<= 1) {
            sums[i] += __shfl_xor(sums[i], off);
            sumq[i] += __shfl_xor(sumq[i], off);
        }
        if (lane == 0) {
            redS[w + 8 * i] = sums[i];   // k = w + 8i; row = k/3
            redQ[w + 8 * i] = sumq[i];
        }
    }
    __syncthreads();                                // B4: partials ready
    if (tid < ROWS) {
        float S = redS[3 * tid] + redS[3 * tid + 1] + redS[3 * tid + 2];
        float Q = redQ[3 * tid] + redQ[3 * tid + 1] + redQ[3 * tid + 2];
        float mean = S * (1.0f / (float)H);
        float var  = Q * (1.0f / (float)H) - mean * mean;
        statsM[tid] = mean;
        statsR[tid] = rsqrtf(var + 1e-5f);
    }
    __syncthreads();                                // B5: stats ready

    // ---- normalize y (in regs) + write out, fully coalesced
#pragma unroll
    for (int i = 0; i < 6; ++i) {
        int c  = tid + NTHREADS * i;
        int r  = c / 192;
        int c8 = c - r * 192;
        int col = c8 * 8;
        float mean = statsM[r];
        float rstd = statsR[r];
        const float4* gp = reinterpret_cast<const float4*>(gamma + col);
        const float4* bp = reinterpret_cast<const float4*>(beta + col);
        float4 g0 = gp[0], g1 = gp[1];
        float4 b0 = bp[0], b1 = bp[1];
        float4 o0, o1;
        o0.x = (va[i].x - mean) * rstd * g0.x + b0.x;
        o0.y = (va[i].y - mean) * rstd * g0.y + b0.y;
        o0.z = (va[i].z - mean) * rstd * g0.z + b0.z;
        o0.w = (va[i].w - mean) * rstd * g0.w + b0.w;
        o1.x = (vb[i].x - mean) * rstd * g1.x + b1.x;
        o1.y = (vb[i].y - mean) * rstd * g1.y + b1.y;
        o1.z = (vb[i].z - mean) * rstd * g1.z + b1.z;
        o1.w = (vb[i].w - mean) * rstd * g1.w + b1.w;
        float4* op = reinterpret_cast<float4*>(out + (row0 + r) * H + col);
        op[0] = o0;
        op[1] = o1;
    }
}

extern "C" void kernel_launch(void* const* d_in, const int* in_sizes, int n_in,
                              void* d_out, int out_size, void* d_ws, size_t ws_size,
                              hipStream_t stream) {
    const float* hs    = (const float*)d_in[0];
    const float* wd    = (const float*)d_in[1];
    const float* wu    = (const float*)d_in[2];
    const float* gam   = (const float*)d_in[3];
    const float* bet   = (const float*)d_in[4];
    float* out = (float*)d_out;

    char* wdp8 = (char*)d_ws;
    char* wup8 = (char*)d_ws + (size_t)128 * H;   // 196608 B each

    pack_weights<<<192, 256, 0, stream>>>(wd, wu, wdp8, wup8);
    fused_adapter<<<NBLOCKS, NTHREADS, 0, stream>>>(hs, wdp8, wup8, gam, bet, out);
}

// Round 7
// 71.541 us; speedup vs baseline: 1.1200x; 1.1200x over previous
//
#include <hip/hip_runtime.h>

#define H 1536
#define BD 128
#define ROWS 16
#define NTHREADS 512
#define NBLOCKS 1024   // 16384 rows / 16

using f16x8 = _Float16 __attribute__((ext_vector_type(8)));
using f32x4 = float __attribute__((ext_vector_type(4)));
using i64x2 = long __attribute__((ext_vector_type(2)));

// Weights |w| <= 6e-4 are BELOW e4m3's denormal floor (2^-9) -> pre-scale by
// 2^14. t stored as t*2^7 in fp8; x stored as x*2^17 in fp8; descale 2^-17.
#define WD_SCALE 16384.0f           // 2^14
#define T8_SCALE (1.0f/128.0f)      // acc1(=t*2^14) * 2^-7 = t*2^7
#define X8_STORE (1.0f/16.0f)       // acc2(=x*2^21) * 2^-4 = x*2^17 (max ~45 < 448)
#define XF_SCALE (1.0f/131072.0f)   // 2^-17

// ---------------------------------------------------------------------------
// Kernel 0: pack weights fp32 -> fp8(e4m3, x2^14), pair-interleaved fragment
// order (unchanged from R5, verified).
// ---------------------------------------------------------------------------
__global__ __launch_bounds__(256) void pack_weights(const float* __restrict__ wd,
                                                    const float* __restrict__ wu,
                                                    char* __restrict__ wdp8,
                                                    char* __restrict__ wup8) {
    int f = blockIdx.x * 256 + threadIdx.x;   // 0..49151
    const float* src;
    char* dst;
    if (f < 24576) {
        int w = f / 3072, rem = f - w * 3072;
        int ph = rem >> 6, l = rem & 63;      // ph = frag index 0..47
        int row = 16 * w + (l & 15);
        int col = 32 * ph + 8 * (l >> 4);
        src = wd + (size_t)row * H + col;     // Wd is [128][1536]
        int p = ph >> 1, half = ph & 1;
        dst = wdp8 + (((size_t)(w * 24 + p) * 64 + l) * 16 + half * 8);
    } else {
        int g = f - 24576;
        int w = g / 3072, rem = g - w * 3072;
        int t2 = rem >> 6, l = rem & 63;      // t2 = nf*4 + kf
        int nf = t2 >> 2, kf = t2 & 3;
        int row = 192 * w + 16 * nf + (l & 15);
        int col = 32 * kf + 8 * (l >> 4);
        src = wu + (size_t)row * BD + col;    // Wu is [1536][128]
        int q = nf * 2 + (kf >> 1), half = kf & 1;
        dst = wup8 + (((size_t)(w * 24 + q) * 64 + l) * 16 + half * 8);
    }
    float4 v0 = reinterpret_cast<const float4*>(src)[0];
    float4 v1 = reinterpret_cast<const float4*>(src)[1];
    int i0 = __builtin_amdgcn_cvt_pk_fp8_f32(v0.x * WD_SCALE, v0.y * WD_SCALE, 0, false);
    i0     = __builtin_amdgcn_cvt_pk_fp8_f32(v0.z * WD_SCALE, v0.w * WD_SCALE, i0, true);
    int i1 = __builtin_amdgcn_cvt_pk_fp8_f32(v1.x * WD_SCALE, v1.y * WD_SCALE, 0, false);
    i1     = __builtin_amdgcn_cvt_pk_fp8_f32(v1.z * WD_SCALE, v1.w * WD_SCALE, i1, true);
    int2 st = {i0, i1};
    *reinterpret_cast<int2*>(dst) = st;
}

// ---------------------------------------------------------------------------
// Fused adapter, 3 barriers total. Nothing lives in registers across any
// barrier (R6's reg-resident hs spilled: VGPR=64 + 41MB scratch writes).
// hs is read twice from global (L3-resident, 256MB >> 100MB). Final phase:
// one row per 32 lanes -> stats via shfl_xor, no LDS, no extra barriers.
// ---------------------------------------------------------------------------
__global__ __launch_bounds__(NTHREADS, 4) void fused_adapter(
    const float* __restrict__ hs,
    const char* __restrict__ wdp8,
    const char* __restrict__ wup8,
    const float* __restrict__ gamma,
    const float* __restrict__ beta,
    float* __restrict__ out)
{
    __shared__ alignas(16) char smem[26624];
    char* hsa8 = smem;                // [48 frag][64 lane][8B] fp8 A-copy
    char* x8   = smem;                // overlay: [16][1536] fp8 x (after B2)
    char* tb8  = smem + 24576;        // [4 frag][64][8B]

    const int tid  = threadIdx.x;
    const int lane = tid & 63;
    const int w    = tid >> 6;        // wave 0..7
    const int l15  = lane & 15;
    const int lk   = lane >> 4;       // 0..3
    const long row0 = (long)blockIdx.x * ROWS;
    const float* hsblk = hs + row0 * H;

    const i64x2* wp2 = reinterpret_cast<const i64x2*>(wdp8) + (size_t)w * 24 * 64 + lane;
    const i64x2* up2 = reinterpret_cast<const i64x2*>(wup8) + (size_t)w * 24 * 64 + lane;

    // ---- prefetch first 4 Wd pairs (hides L2 latency under staging)
    i64x2 bq[4];
    bq[0] = wp2[0 * 64]; bq[1] = wp2[1 * 64]; bq[2] = wp2[2 * 64]; bq[3] = wp2[3 * 64];

    // ---- stage: hs -> fp8 hsa8 in GEMM1 A-fragment order (regs die at B1)
    {
        float4 va[6], vb[6];
#pragma unroll
        for (int i = 0; i < 6; ++i) {
            int c  = tid + NTHREADS * i;
            int r  = c / 192;
            int c8 = c - r * 192;
            const float4* p = reinterpret_cast<const float4*>(hsblk + (long)r * H + c8 * 8);
            va[i] = p[0];
            vb[i] = p[1];
        }
#pragma unroll
        for (int i = 0; i < 6; ++i) {
            int c  = tid + NTHREADS * i;
            int r  = c / 192;
            int c8 = c - r * 192;
            int j0 = __builtin_amdgcn_cvt_pk_fp8_f32(va[i].x, va[i].y, 0, false);
            j0     = __builtin_amdgcn_cvt_pk_fp8_f32(va[i].z, va[i].w, j0, true);
            int j1 = __builtin_amdgcn_cvt_pk_fp8_f32(vb[i].x, vb[i].y, 0, false);
            j1     = __builtin_amdgcn_cvt_pk_fp8_f32(vb[i].z, vb[i].w, j1, true);
            int kk = c8 >> 2, m = c8 & 3;
            int al = (16 * m + r) ^ ((kk & 15) << 1);   // bank swizzle (verified)
            int2 stv = {j0, j1};
            *reinterpret_cast<int2*>(&hsa8[(kk * 64 + al) * 8]) = stv;
        }
    }
    __syncthreads();                                // B1: hsa8 ready

    // ---- GEMM1 (fp8): t = hs @ Wd^T; wave w owns t-cols 16w..16w+15.
    f32x4 accv[4] = {{0,0,0,0},{0,0,0,0},{0,0,0,0},{0,0,0,0}};
#pragma unroll
    for (int p = 0; p < 24; ++p) {
        int kk0 = 2 * p, kk1 = 2 * p + 1;
        long alo = *reinterpret_cast<const long*>(&hsa8[(kk0 * 64 + (lane ^ ((kk0 & 15) << 1))) * 8]);
        long ahi = *reinterpret_cast<const long*>(&hsa8[(kk1 * 64 + (lane ^ ((kk1 & 15) << 1))) * 8]);
        i64x2 b = bq[p & 3];
        if (p + 4 < 24) bq[p & 3] = wp2[(p + 4) * 64];
        f32x4 a = accv[p & 3];
        a = __builtin_amdgcn_mfma_f32_16x16x32_fp8_fp8(alo, b[0], a, 0, 0, 0);
        a = __builtin_amdgcn_mfma_f32_16x16x32_fp8_fp8(ahi, b[1], a, 0, 0, 0);
        accv[p & 3] = a;
    }

    // ---- prefetch first 4 Wu pairs (covers tb8 round-trip + barrier)
    i64x2 uq[4];
    uq[0] = up2[0 * 64]; uq[1] = up2[1 * 64]; uq[2] = up2[2 * 64]; uq[3] = up2[3 * 64];

    // ---- t -> fp8 tb8 (t*2^7), GEMM2 A-fragment order (verified mapping)
    {
        f32x4 a1 = (accv[0] + accv[1]) + (accv[2] + accv[3]);
        int p0 = __builtin_amdgcn_cvt_pk_fp8_f32(a1[0] * T8_SCALE, a1[1] * T8_SCALE, 0, false);
        int p1 = __builtin_amdgcn_cvt_pk_fp8_f32(a1[2] * T8_SCALE, a1[3] * T8_SCALE, 0, false);
        int kk2 = w >> 1;
        int lane_hi = 2 * (w & 1) + (l15 >> 3);
        int e8 = l15 & 7;
        int base = (kk2 * 64 + 16 * lane_hi + 4 * lk) * 8 + e8;
        tb8[base + 0 * 8] = (char)(p0 & 0xFF);
        tb8[base + 1 * 8] = (char)((p0 >> 8) & 0xFF);
        tb8[base + 2 * 8] = (char)(p1 & 0xFF);
        tb8[base + 3 * 8] = (char)((p1 >> 8) & 0xFF);
    }
    __syncthreads();                                // B2: tb8 ready (GEMM1 done)

    long a2f8[4];
#pragma unroll
    for (int kf = 0; kf < 4; ++kf)
        a2f8[kf] = *reinterpret_cast<const long*>(&tb8[(kf * 64 + lane) * 8]);

    // ---- GEMM2 (fp8): x = t @ Wu^T -> fp8 x8 (overlay of hsa8; all hsa8
    // reads completed before B2).
#pragma unroll
    for (int nf = 0; nf < 12; ++nf) {
        i64x2 u0 = uq[(2 * nf) & 3];
        i64x2 u1 = uq[(2 * nf + 1) & 3];
        if (2 * nf + 4 < 24) uq[(2 * nf) & 3]     = up2[(2 * nf + 4) * 64];
        if (2 * nf + 5 < 24) uq[(2 * nf + 1) & 3] = up2[(2 * nf + 5) * 64];
        f32x4 acc = {0.f, 0.f, 0.f, 0.f};
        acc = __builtin_amdgcn_mfma_f32_16x16x32_fp8_fp8(a2f8[0], u0[0], acc, 0, 0, 0);
        acc = __builtin_amdgcn_mfma_f32_16x16x32_fp8_fp8(a2f8[1], u0[1], acc, 0, 0, 0);
        acc = __builtin_amdgcn_mfma_f32_16x16x32_fp8_fp8(a2f8[2], u1[0], acc, 0, 0, 0);
        acc = __builtin_amdgcn_mfma_f32_16x16x32_fp8_fp8(a2f8[3], u1[1], acc, 0, 0, 0);
        int cn = 192 * w + 16 * nf + l15;
        int p0 = __builtin_amdgcn_cvt_pk_fp8_f32(acc[0] * X8_STORE, acc[1] * X8_STORE, 0, false);
        int p1 = __builtin_amdgcn_cvt_pk_fp8_f32(acc[2] * X8_STORE, acc[3] * X8_STORE, 0, false);
        x8[(4 * lk + 0) * H + cn] = (char)(p0 & 0xFF);
        x8[(4 * lk + 1) * H + cn] = (char)((p0 >> 8) & 0xFF);
        x8[(4 * lk + 2) * H + cn] = (char)(p1 & 0xFF);
        x8[(4 * lk + 3) * H + cn] = (char)((p1 >> 8) & 0xFF);
    }
    __syncthreads();                                // B3: x8 ready

    // ---- final: re-read hs (L3-hit), y = hs + x; one row per 32 lanes ->
    // stats via shfl_xor only (no LDS, no barriers); normalize + store.
    {
        const int fr  = tid >> 5;         // row 0..15
        const int cid = tid & 31;
        const float* hsrow = hsblk + (long)fr * H;
        float* orow = out + (row0 + fr) * H;
        float4 ya[6], yb[6];
#pragma unroll
        for (int k = 0; k < 6; ++k) {
            int col = 8 * (cid + 32 * k);
            const float4* p = reinterpret_cast<const float4*>(hsrow + col);
            ya[k] = p[0];
            yb[k] = p[1];
        }
        float s = 0.f, q = 0.f;
#pragma unroll
        for (int k = 0; k < 6; ++k) {
            int col = 8 * (cid + 32 * k);
            int2 xw = *reinterpret_cast<const int2*>(&x8[fr * H + col]);
            ya[k].x += __builtin_amdgcn_cvt_f32_fp8(xw.x, 0) * XF_SCALE;
            ya[k].y += __builtin_amdgcn_cvt_f32_fp8(xw.x, 1) * XF_SCALE;
            ya[k].z += __builtin_amdgcn_cvt_f32_fp8(xw.x, 2) * XF_SCALE;
            ya[k].w += __builtin_amdgcn_cvt_f32_fp8(xw.x, 3) * XF_SCALE;
            yb[k].x += __builtin_amdgcn_cvt_f32_fp8(xw.y, 0) * XF_SCALE;
            yb[k].y += __builtin_amdgcn_cvt_f32_fp8(xw.y, 1) * XF_SCALE;
            yb[k].z += __builtin_amdgcn_cvt_f32_fp8(xw.y, 2) * XF_SCALE;
            yb[k].w += __builtin_amdgcn_cvt_f32_fp8(xw.y, 3) * XF_SCALE;
            s += (ya[k].x + ya[k].y) + (ya[k].z + ya[k].w)
               + (yb[k].x + yb[k].y) + (yb[k].z + yb[k].w);
            q += (ya[k].x * ya[k].x + ya[k].y * ya[k].y)
               + (ya[k].z * ya[k].z + ya[k].w * ya[k].w)
               + (yb[k].x * yb[k].x + yb[k].y * yb[k].y)
               + (yb[k].z * yb[k].z + yb[k].w * yb[k].w);
        }
#pragma unroll
        for (int off = 1; off < 32; off <<= 1) {
            s += __shfl_xor(s, off);
            q += __shfl_xor(q, off);
        }
        float mean = s * (1.0f / (float)H);
        float var  = q * (1.0f / (float)H) - mean * mean;
        float rstd = rsqrtf(var + 1e-5f);
#pragma unroll
        for (int k = 0; k < 6; ++k) {
            int col = 8 * (cid + 32 * k);
            const float4* gp = reinterpret_cast<const float4*>(gamma + col);
            const float4* bp = reinterpret_cast<const float4*>(beta + col);
            float4 g0 = gp[0], g1 = gp[1];
            float4 b0 = bp[0], b1 = bp[1];
            float4 o0, o1;
            o0.x = (ya[k].x - mean) * rstd * g0.x + b0.x;
            o0.y = (ya[k].y - mean) * rstd * g0.y + b0.y;
            o0.z = (ya[k].z - mean) * rstd * g0.z + b0.z;
            o0.w = (ya[k].w - mean) * rstd * g0.w + b0.w;
            o1.x = (yb[k].x - mean) * rstd * g1.x + b1.x;
            o1.y = (yb[k].y - mean) * rstd * g1.y + b1.y;
            o1.z = (yb[k].z - mean) * rstd * g1.z + b1.z;
            o1.w = (yb[k].w - mean) * rstd * g1.w + b1.w;
            float4* op = reinterpret_cast<float4*>(orow + col);
            op[0] = o0;
            op[1] = o1;
        }
    }
}

extern "C" void kernel_launch(void* const* d_in, const int* in_sizes, int n_in,
                              void* d_out, int out_size, void* d_ws, size_t ws_size,
                              hipStream_t stream) {
    const float* hs    = (const float*)d_in[0];
    const float* wd    = (const float*)d_in[1];
    const float* wu    = (const float*)d_in[2];
    const float* gam   = (const float*)d_in[3];
    const float* bet   = (const float*)d_in[4];
    float* out = (float*)d_out;

    char* wdp8 = (char*)d_ws;
    char* wup8 = (char*)d_ws + (size_t)128 * H;   // 196608 B each

    pack_weights<<<192, 256, 0, stream>>>(wd, wu, wdp8, wup8);
    fused_adapter<<<NBLOCKS, NTHREADS, 0, stream>>>(hs, wdp8, wup8, gam, bet, out);
}

// Round 8
// 71.303 us; speedup vs baseline: 1.1237x; 1.0033x over previous
//
#include <hip/hip_runtime.h>

#define H 1536
#define BD 128
#define ROWS 16
#define NTHREADS 512
#define NBLOCKS 1024   // 16384 rows / 16

using f16x8 = _Float16 __attribute__((ext_vector_type(8)));
using f32x4 = float __attribute__((ext_vector_type(4)));
using i64x2 = long __attribute__((ext_vector_type(2)));

// Weights |w| <= 6e-4 are BELOW e4m3's denormal floor (2^-9) -> pre-scale by
// 2^14. t stored as t*2^7 in fp8; x stored as x*2^17 in fp8; descale 2^-17.
#define WD_SCALE 16384.0f           // 2^14
#define T8_SCALE (1.0f/128.0f)      // acc1(=t*2^14) * 2^-7 = t*2^7
#define X8_STORE (1.0f/16.0f)       // acc2(=x*2^21) * 2^-4 = x*2^17 (max ~45 < 448)
#define XF_SCALE (1.0f/131072.0f)   // 2^-17

// ---------------------------------------------------------------------------
// Kernel 0: pack weights fp32 -> fp8(e4m3, x2^14), pair-interleaved fragment
// order (unchanged since R5, verified). Fragments serve as A-operands after
// the operand swap — A and B lane mappings are identical.
// ---------------------------------------------------------------------------
__global__ __launch_bounds__(256) void pack_weights(const float* __restrict__ wd,
                                                    const float* __restrict__ wu,
                                                    char* __restrict__ wdp8,
                                                    char* __restrict__ wup8) {
    int f = blockIdx.x * 256 + threadIdx.x;   // 0..49151
    const float* src;
    char* dst;
    if (f < 24576) {
        int w = f / 3072, rem = f - w * 3072;
        int ph = rem >> 6, l = rem & 63;      // ph = frag index 0..47
        int row = 16 * w + (l & 15);
        int col = 32 * ph + 8 * (l >> 4);
        src = wd + (size_t)row * H + col;     // Wd is [128][1536]
        int p = ph >> 1, half = ph & 1;
        dst = wdp8 + (((size_t)(w * 24 + p) * 64 + l) * 16 + half * 8);
    } else {
        int g = f - 24576;
        int w = g / 3072, rem = g - w * 3072;
        int t2 = rem >> 6, l = rem & 63;      // t2 = nf*4 + kf
        int nf = t2 >> 2, kf = t2 & 3;
        int row = 192 * w + 16 * nf + (l & 15);
        int col = 32 * kf + 8 * (l >> 4);
        src = wu + (size_t)row * BD + col;    // Wu is [1536][128]
        int q = nf * 2 + (kf >> 1), half = kf & 1;
        dst = wup8 + (((size_t)(w * 24 + q) * 64 + l) * 16 + half * 8);
    }
    float4 v0 = reinterpret_cast<const float4*>(src)[0];
    float4 v1 = reinterpret_cast<const float4*>(src)[1];
    int i0 = __builtin_amdgcn_cvt_pk_fp8_f32(v0.x * WD_SCALE, v0.y * WD_SCALE, 0, false);
    i0     = __builtin_amdgcn_cvt_pk_fp8_f32(v0.z * WD_SCALE, v0.w * WD_SCALE, i0, true);
    int i1 = __builtin_amdgcn_cvt_pk_fp8_f32(v1.x * WD_SCALE, v1.y * WD_SCALE, 0, false);
    i1     = __builtin_amdgcn_cvt_pk_fp8_f32(v1.z * WD_SCALE, v1.w * WD_SCALE, i1, true);
    int2 st = {i0, i1};
    *reinterpret_cast<int2*>(dst) = st;
}

// ---------------------------------------------------------------------------
// Fused adapter, 3 barriers, nothing live in regs across barriers.
// OPERAND-SWAPPED MFMAs: mfma(W_frag, hs/t_frag, acc) -> D lane&15 = ROW,
// reg j = 4 consecutive COLS -> epilogues pack 4 fp8 bytes into one
// ds_write_b32 (was 48 ds_write_b8 in GEMM2). x8 uses a 16B-granule XOR
// swizzle consistent on write(4B) and read(8B) sides.
// ---------------------------------------------------------------------------
__global__ __launch_bounds__(NTHREADS, 4) void fused_adapter(
    const float* __restrict__ hs,
    const char* __restrict__ wdp8,
    const char* __restrict__ wup8,
    const float* __restrict__ gamma,
    const float* __restrict__ beta,
    float* __restrict__ out)
{
    __shared__ alignas(16) char smem[26624];
    char* hsa8 = smem;                // [48 frag][64 lane][8B] fp8 A-copy
    char* x8   = smem;                // overlay: [16][1536] fp8 x (after B2)
    char* tb8  = smem + 24576;        // [4 frag][64][8B]

    const int tid  = threadIdx.x;
    const int lane = tid & 63;
    const int w    = tid >> 6;        // wave 0..7
    const int l15  = lane & 15;
    const int lk   = lane >> 4;       // 0..3
    const long row0 = (long)blockIdx.x * ROWS;
    const float* hsblk = hs + row0 * H;

    const i64x2* wp2 = reinterpret_cast<const i64x2*>(wdp8) + (size_t)w * 24 * 64 + lane;
    const i64x2* up2 = reinterpret_cast<const i64x2*>(wup8) + (size_t)w * 24 * 64 + lane;

    // ---- stage: issue all hs loads first (12-deep MLP), then Wd prefetch,
    // then convert. Regs die at B1.
    {
        float4 va[6], vb[6];
#pragma unroll
        for (int i = 0; i < 6; ++i) {
            int c  = tid + NTHREADS * i;
            int r  = c / 192;
            int c8 = c - r * 192;
            const float4* p = reinterpret_cast<const float4*>(hsblk + (long)r * H + c8 * 8);
            va[i] = p[0];
            vb[i] = p[1];
        }
        __asm__ volatile("" ::: "memory");   // keep load issue order ahead of bq
#pragma unroll
        for (int i = 0; i < 6; ++i) {
            int c  = tid + NTHREADS * i;
            int r  = c / 192;
            int c8 = c - r * 192;
            int j0 = __builtin_amdgcn_cvt_pk_fp8_f32(va[i].x, va[i].y, 0, false);
            j0     = __builtin_amdgcn_cvt_pk_fp8_f32(va[i].z, va[i].w, j0, true);
            int j1 = __builtin_amdgcn_cvt_pk_fp8_f32(vb[i].x, vb[i].y, 0, false);
            j1     = __builtin_amdgcn_cvt_pk_fp8_f32(vb[i].z, vb[i].w, j1, true);
            int kk = c8 >> 2, m = c8 & 3;
            int al = (16 * m + r) ^ ((kk & 15) << 1);   // bank swizzle (verified)
            int2 stv = {j0, j1};
            *reinterpret_cast<int2*>(&hsa8[(kk * 64 + al) * 8]) = stv;
        }
    }

    // ---- Wd prefetch, 8-deep rotation (distance ~8 iters > L2 latency)
    i64x2 bq[8];
#pragma unroll
    for (int i = 0; i < 8; ++i) bq[i] = wp2[i * 64];

    __syncthreads();                                // B1: hsa8 ready

    // ---- GEMM1 (fp8, swapped): D lane l15 = t-row, reg j -> t-col 16w+4lk+j
    f32x4 accv[4] = {{0,0,0,0},{0,0,0,0},{0,0,0,0},{0,0,0,0}};
#pragma unroll
    for (int p = 0; p < 24; ++p) {
        int kk0 = 2 * p, kk1 = 2 * p + 1;
        long blo = *reinterpret_cast<const long*>(&hsa8[(kk0 * 64 + (lane ^ ((kk0 & 15) << 1))) * 8]);
        long bhi = *reinterpret_cast<const long*>(&hsa8[(kk1 * 64 + (lane ^ ((kk1 & 15) << 1))) * 8]);
        i64x2 b = bq[p & 7];
        if (p + 8 < 24) bq[p & 7] = wp2[(p + 8) * 64];
        f32x4 a = accv[p & 3];
        a = __builtin_amdgcn_mfma_f32_16x16x32_fp8_fp8(b[0], blo, a, 0, 0, 0);
        a = __builtin_amdgcn_mfma_f32_16x16x32_fp8_fp8(b[1], bhi, a, 0, 0, 0);
        accv[p & 3] = a;
    }

    // ---- Wu prefetch, 12-deep (all pairs 0..11 in flight across B2)
    i64x2 uq[12];
#pragma unroll
    for (int i = 0; i < 12; ++i) uq[i] = up2[i * 64];

    // ---- t -> tb8: ONE packed ds_write_b32 per thread (swapped layout).
    // lane holds t[r=l15][c0..c0+3], c0 = 16w+4lk; target frag layout:
    // frag kf, lane hi*16+r, byte (c0&7)+j  with c0 = 32kf + 8hi + (c0&7).
    {
        f32x4 a1 = (accv[0] + accv[1]) + (accv[2] + accv[3]);
        int p0 = __builtin_amdgcn_cvt_pk_fp8_f32(a1[0] * T8_SCALE, a1[1] * T8_SCALE, 0, false);
        int p1 = __builtin_amdgcn_cvt_pk_fp8_f32(a1[2] * T8_SCALE, a1[3] * T8_SCALE, 0, false);
        unsigned word = (unsigned)(p0 & 0xFFFF) | ((unsigned)(p1 & 0xFFFF) << 16);
        int c0 = 16 * w + 4 * lk;
        int kf = c0 >> 5, hi = (c0 >> 3) & 3, off = c0 & 7;
        *reinterpret_cast<unsigned*>(&tb8[(kf * 64 + hi * 16 + l15) * 8 + off]) = word;
    }
    __syncthreads();                                // B2: tb8 ready (GEMM1 done)

    long a2f8[4];
#pragma unroll
    for (int kf = 0; kf < 4; ++kf)
        a2f8[kf] = *reinterpret_cast<const long*>(&tb8[(kf * 64 + lane) * 8]);

    // ---- GEMM2 (fp8, swapped): D lane l15 = x-row, reg j -> x-col cx+j.
    // Epilogue: 1 packed ds_write_b32/nf into XOR-swizzled row-major x8.
#pragma unroll
    for (int nf = 0; nf < 12; ++nf) {
        i64x2 u0 = uq[(2 * nf) % 12];
        i64x2 u1 = uq[(2 * nf + 1) % 12];
        if (2 * nf + 12 < 24) uq[(2 * nf) % 12]     = up2[(2 * nf + 12) * 64];
        if (2 * nf + 13 < 24) uq[(2 * nf + 1) % 12] = up2[(2 * nf + 13) * 64];
        f32x4 acc = {0.f, 0.f, 0.f, 0.f};
        acc = __builtin_amdgcn_mfma_f32_16x16x32_fp8_fp8(u0[0], a2f8[0], acc, 0, 0, 0);
        acc = __builtin_amdgcn_mfma_f32_16x16x32_fp8_fp8(u0[1], a2f8[1], acc, 0, 0, 0);
        acc = __builtin_amdgcn_mfma_f32_16x16x32_fp8_fp8(u1[0], a2f8[2], acc, 0, 0, 0);
        acc = __builtin_amdgcn_mfma_f32_16x16x32_fp8_fp8(u1[1], a2f8[3], acc, 0, 0, 0);
        int p0 = __builtin_amdgcn_cvt_pk_fp8_f32(acc[0] * X8_STORE, acc[1] * X8_STORE, 0, false);
        int p1 = __builtin_amdgcn_cvt_pk_fp8_f32(acc[2] * X8_STORE, acc[3] * X8_STORE, 0, false);
        unsigned word = (unsigned)(p0 & 0xFFFF) | ((unsigned)(p1 & 0xFFFF) << 16);
        int cx = 192 * w + 16 * nf + 4 * lk;
        *reinterpret_cast<unsigned*>(&x8[l15 * H + (cx ^ ((l15 & 7) << 4))]) = word;
    }
    __syncthreads();                                // B3: x8 ready

    // ---- final: re-read hs (L3-hit), y = hs + x; one row per 32 lanes ->
    // stats via shfl_xor only; normalize + store. x8 read applies the same
    // 16B-granule XOR swizzle (8B reads stay within a 16B granule).
    {
        const int fr  = tid >> 5;         // row 0..15
        const int cid = tid & 31;
        const int fswz = (fr & 7) << 4;
        const float* hsrow = hsblk + (long)fr * H;
        float* orow = out + (row0 + fr) * H;
        float4 ya[6], yb[6];
#pragma unroll
        for (int k = 0; k < 6; ++k) {
            int col = 8 * (cid + 32 * k);
            const float4* p = reinterpret_cast<const float4*>(hsrow + col);
            ya[k] = p[0];
            yb[k] = p[1];
        }
        float s = 0.f, q = 0.f;
#pragma unroll
        for (int k = 0; k < 6; ++k) {
            int col = 8 * (cid + 32 * k);
            int2 xw = *reinterpret_cast<const int2*>(&x8[fr * H + (col ^ fswz)]);
            ya[k].x += __builtin_amdgcn_cvt_f32_fp8(xw.x, 0) * XF_SCALE;
            ya[k].y += __builtin_amdgcn_cvt_f32_fp8(xw.x, 1) * XF_SCALE;
            ya[k].z += __builtin_amdgcn_cvt_f32_fp8(xw.x, 2) * XF_SCALE;
            ya[k].w += __builtin_amdgcn_cvt_f32_fp8(xw.x, 3) * XF_SCALE;
            yb[k].x += __builtin_amdgcn_cvt_f32_fp8(xw.y, 0) * XF_SCALE;
            yb[k].y += __builtin_amdgcn_cvt_f32_fp8(xw.y, 1) * XF_SCALE;
            yb[k].z += __builtin_amdgcn_cvt_f32_fp8(xw.y, 2) * XF_SCALE;
            yb[k].w += __builtin_amdgcn_cvt_f32_fp8(xw.y, 3) * XF_SCALE;
            s += (ya[k].x + ya[k].y) + (ya[k].z + ya[k].w)
               + (yb[k].x + yb[k].y) + (yb[k].z + yb[k].w);
            q += (ya[k].x * ya[k].x + ya[k].y * ya[k].y)
               + (ya[k].z * ya[k].z + ya[k].w * ya[k].w)
               + (yb[k].x * yb[k].x + yb[k].y * yb[k].y)
               + (yb[k].z * yb[k].z + yb[k].w * yb[k].w);
        }
#pragma unroll
        for (int off = 1; off < 32; off <<= 1) {
            s += __shfl_xor(s, off);
            q += __shfl_xor(q, off);
        }
        float mean = s * (1.0f / (float)H);
        float var  = q * (1.0f / (float)H) - mean * mean;
        float rstd = rsqrtf(var + 1e-5f);
#pragma unroll
        for (int k = 0; k < 6; ++k) {
            int col = 8 * (cid + 32 * k);
            const float4* gp = reinterpret_cast<const float4*>(gamma + col);
            const float4* bp = reinterpret_cast<const float4*>(beta + col);
            float4 g0 = gp[0], g1 = gp[1];
            float4 b0 = bp[0], b1 = bp[1];
            float4 o0, o1;
            o0.x = (ya[k].x - mean) * rstd * g0.x + b0.x;
            o0.y = (ya[k].y - mean) * rstd * g0.y + b0.y;
            o0.z = (ya[k].z - mean) * rstd * g0.z + b0.z;
            o0.w = (ya[k].w - mean) * rstd * g0.w + b0.w;
            o1.x = (yb[k].x - mean) * rstd * g1.x + b1.x;
            o1.y = (yb[k].y - mean) * rstd * g1.y + b1.y;
            o1.z = (yb[k].z - mean) * rstd * g1.z + b1.z;
            o1.w = (yb[k].w - mean) * rstd * g1.w + b1.w;
            float4* op = reinterpret_cast<float4*>(orow + col);
            op[0] = o0;
            op[1] = o1;
        }
    }
}

extern "C" void kernel_launch(void* const* d_in, const int* in_sizes, int n_in,
                              void* d_out, int out_size, void* d_ws, size_t ws_size,
                              hipStream_t stream) {
    const float* hs    = (const float*)d_in[0];
    const float* wd    = (const float*)d_in[1];
    const float* wu    = (const float*)d_in[2];
    const float* gam   = (const float*)d_in[3];
    const float* bet   = (const float*)d_in[4];
    float* out = (float*)d_out;

    char* wdp8 = (char*)d_ws;
    char* wup8 = (char*)d_ws + (size_t)128 * H;   // 196608 B each

    pack_weights<<<192, 256, 0, stream>>>(wd, wu, wdp8, wup8);
    fused_adapter<<<NBLOCKS, NTHREADS, 0, stream>>>(hs, wdp8, wup8, gam, bet, out);
}